// Round 1
// baseline (159.029 us; speedup 1.0000x reference)
//
#include <hip/hip_runtime.h>
#include <hip/hip_bf16.h>

#define B_ 256
#define S_ 256
#define T_ 128
#define START_ 126
#define STOP_ 127

typedef __attribute__((ext_vector_type(8))) short short8;
typedef __attribute__((ext_vector_type(4))) float f32x4;

// float -> bf16 bits with round-to-nearest-even
__device__ __forceinline__ unsigned short f2bf(float f) {
    unsigned u = __float_as_uint(f);
    unsigned r = (u + 0x7FFFu + ((u >> 16) & 1u)) >> 16;
    return (unsigned short)r;
}

__device__ __forceinline__ float bf2f(unsigned short h) {
    return __uint_as_float(((unsigned)h) << 16);
}

// max-reduce across the 16-lane DPP row; all lanes end with the row max.
__device__ __forceinline__ float red16max(float x) {
#if __has_builtin(__builtin_amdgcn_mov_dpp)
    x = fmaxf(x, __int_as_float(__builtin_amdgcn_mov_dpp(__float_as_int(x), 0x128, 0xF, 0xF, true))); // row_ror:8
    x = fmaxf(x, __int_as_float(__builtin_amdgcn_mov_dpp(__float_as_int(x), 0x124, 0xF, 0xF, true))); // row_ror:4
    x = fmaxf(x, __int_as_float(__builtin_amdgcn_mov_dpp(__float_as_int(x), 0x122, 0xF, 0xF, true))); // row_ror:2
    x = fmaxf(x, __int_as_float(__builtin_amdgcn_mov_dpp(__float_as_int(x), 0x121, 0xF, 0xF, true))); // row_ror:1
#else
    x = fmaxf(x, __shfl_xor(x, 8, 16));
    x = fmaxf(x, __shfl_xor(x, 4, 16));
    x = fmaxf(x, __shfl_xor(x, 2, 16));
    x = fmaxf(x, __shfl_xor(x, 1, 16));
#endif
    return x;
}

// Block-wide float sum over 256 threads (4 waves). Returns the sum to all
// threads. Internally barriered; safe to call back-to-back.
__device__ __forceinline__ float block_sum(float v, float* red, int tid) {
    #pragma unroll
    for (int o = 32; o; o >>= 1) v += __shfl_down(v, o, 64);
    __syncthreads();                    // protect red from any previous use
    if ((tid & 63) == 0) red[tid >> 6] = v;
    __syncthreads();
    float r = (red[0] + red[1]) + (red[2] + red[3]);
    __syncthreads();                    // allow immediate reuse of red
    return r;
}

__global__ __launch_bounds__(256) void crf_fwd(
    const float* __restrict__ feats,      // [B, S, T]
    const float* __restrict__ trans,      // [T, T]
    const int*   __restrict__ tags,       // [B, S]
    const int*   __restrict__ mask,       // [B, S]
    float* __restrict__ out)              // [1]
{
    const int b    = blockIdx.x;
    const int tid  = threadIdx.x;
    const int lane = tid & 63;
    const int w    = tid >> 6;            // wave 0..3

    __shared__ __align__(16) unsigned short epb[2][T_]; // scaled alpha, bf16, dbuf
    __shared__ float fbuf[2][8][T_];                    // exp(feat) rows, dbuf chunks of 8
    __shared__ float red[4];

    const float* fb_base = feats + (size_t)b * (S_ * T_);

    // j columns owned by this thread: wave w owns n-tiles {2w, 2w+1}
    const int j0 = w * 32 + (lane & 15);
    const int j1 = j0 + 16;
    const int kg = (lane >> 4) * 8;       // k-subrange within each 32-wide k-tile

    // ---- one-time: B fragments = exp(transitions), kept in VGPRs ----
    short8 bfrag[4][2];
    {
        #pragma unroll
        for (int kt = 0; kt < 4; ++kt) {
            #pragma unroll
            for (int nt = 0; nt < 2; ++nt) {
                const int col = w * 32 + nt * 16 + (lane & 15);
                short8 f;
                #pragma unroll
                for (int r = 0; r < 8; ++r) {
                    const int k = kt * 32 + kg + r;
                    f[r] = (short)f2bf(__expf(trans[k * T_ + col]));
                }
                bfrag[kt][nt] = f;
            }
        }
    }

    // ---- stage chunk 0 (rows 0..7) of exp(feat) ----
    {
        const int r = tid >> 5, c = (tid & 31) * 4;
        const float4 v = *(const float4*)&fb_base[tid * 4];
        float4 e;
        e.x = __expf(v.x); e.y = __expf(v.y); e.z = __expf(v.z); e.w = __expf(v.w);
        *(float4*)&fbuf[0][r][c] = e;
    }

    // ---- sequence length (prefix mask => just count) ----
    const int mk  = mask[b * S_ + tid];
    const int len = (int)(block_sum((float)mk, red, tid) + 0.5f); // also makes fbuf[0] visible

    float M;  // running log-scale; identical across all threads

    // ---- init alpha_0: u_j = exp(feat0_j) * exp(trans[START][j]) ----
    {
        float u0 = fbuf[0][0][j0] * __expf(trans[START_ * T_ + j0]);
        float u1 = fbuf[0][0][j1] * __expf(trans[START_ * T_ + j1]);
        float m2 = red16max(fmaxf(u0, u1));
        if (lane == 0) red[w] = m2;
        __syncthreads();
        const float s  = fmaxf(fmaxf(red[0], red[1]), fmaxf(red[2], red[3]));
        const float rs = 1.0f / s;
        if (lane < 16) {
            epb[1][j0] = f2bf(u0 * rs);
            epb[1][j1] = f2bf(u1 * rs);
        }
        M = __logf(s);
        __syncthreads();
    }

    // ---- main recurrence: t = 1 .. len-1 ----
    float4 pre = make_float4(0.f, 0.f, 0.f, 0.f);
    int pend = 0;
    for (int t = 1; t < len; ++t) {
        const int p  = t & 1;
        const int pn = p ^ 1;
        const int bc = (t >> 3) & 1;
        const int tr = t & 7;

        // register prefetch of next 8-row feat chunk (issued 6 steps early)
        if (tr == 1) {
            const int nb = (t >> 3) + 1;
            if (nb < S_ / 8) {
                pre = *(const float4*)&fb_base[nb * (8 * T_) + tid * 4];
                pend = 1;
            }
        }

        // A fragments: broadcast ep across all 16 rows (row-layout immune)
        const short8 a0 = *(const short8*)&epb[p][ 0 + kg];
        const short8 a1 = *(const short8*)&epb[p][32 + kg];
        const short8 a2 = *(const short8*)&epb[p][64 + kg];
        const short8 a3 = *(const short8*)&epb[p][96 + kg];

        f32x4 acc0 = {0.f, 0.f, 0.f, 0.f};
        f32x4 acc1 = {0.f, 0.f, 0.f, 0.f};
        acc0 = __builtin_amdgcn_mfma_f32_16x16x32_bf16(a0, bfrag[0][0], acc0, 0, 0, 0);
        acc0 = __builtin_amdgcn_mfma_f32_16x16x32_bf16(a1, bfrag[1][0], acc0, 0, 0, 0);
        acc0 = __builtin_amdgcn_mfma_f32_16x16x32_bf16(a2, bfrag[2][0], acc0, 0, 0, 0);
        acc0 = __builtin_amdgcn_mfma_f32_16x16x32_bf16(a3, bfrag[3][0], acc0, 0, 0, 0);
        acc1 = __builtin_amdgcn_mfma_f32_16x16x32_bf16(a0, bfrag[0][1], acc1, 0, 0, 0);
        acc1 = __builtin_amdgcn_mfma_f32_16x16x32_bf16(a1, bfrag[1][1], acc1, 0, 0, 0);
        acc1 = __builtin_amdgcn_mfma_f32_16x16x32_bf16(a2, bfrag[2][1], acc1, 0, 0, 0);
        acc1 = __builtin_amdgcn_mfma_f32_16x16x32_bf16(a3, bfrag[3][1], acc1, 0, 0, 0);

        float u0 = acc0[0] * fbuf[bc][tr][j0];
        float u1 = acc1[0] * fbuf[bc][tr][j1];

        // renormalize every 4 steps (worst-case growth ~e^44 < f32 max)
        if ((t & 3) == 0) {
            float m2 = red16max(fmaxf(u0, u1));
            if (lane == 0) red[w] = m2;
            __syncthreads();
            const float s  = fmaxf(fmaxf(red[0], red[1]), fmaxf(red[2], red[3]));
            const float rs = 1.0f / s;
            u0 *= rs; u1 *= rs;
            M += __logf(s);
        }

        if (lane < 16) {
            epb[pn][j0] = f2bf(u0);
            epb[pn][j1] = f2bf(u1);
        }

        // write the prefetched chunk late (latency long hidden)
        if (tr == 7 && pend) {
            const int nb = (t >> 3) + 1;
            const int r = tid >> 5, c = (tid & 31) * 4;
            float4 e;
            e.x = __expf(pre.x); e.y = __expf(pre.y);
            e.z = __expf(pre.z); e.w = __expf(pre.w);
            *(float4*)&fbuf[nb & 1][r][c] = e;
            pend = 0;
        }

        __syncthreads();
    }

    // ---- forward score: M + log( sum_i ep[i] * exp(trans[i][STOP]) ) ----
    const int pf = len & 1;
    float v = 0.f;
    if (tid < T_) {
        v = bf2f(epb[pf][tid]) * __expf(trans[tid * T_ + STOP_]);
    }
    const float ssum = block_sum(v, red, tid);
    const float fwd  = M + __logf(ssum);

    // ---- gold path score ----
    const int tg = tags[b * S_ + tid];
    float g = 0.f;
    if (mk) {
        const int prev = (tid == 0) ? START_ : tags[b * S_ + tid - 1];
        g = fb_base[tid * T_ + tg] + trans[prev * T_ + tg];
    }
    if (tid == len - 1) g += trans[tg * T_ + STOP_];
    const float gold = block_sum(g, red, tid);

    if (tid == 0) atomicAdd(out, fwd - gold);
}

extern "C" void kernel_launch(void* const* d_in, const int* in_sizes, int n_in,
                              void* d_out, int out_size, void* d_ws, size_t ws_size,
                              hipStream_t stream) {
    const float* feats = (const float*)d_in[0];
    const float* trans = (const float*)d_in[1];
    const int*   tags  = (const int*)d_in[2];
    const int*   mask  = (const int*)d_in[3];
    float* out = (float*)d_out;

    // d_out is poisoned before every timed launch; zero it first.
    hipMemsetAsync(out, 0, sizeof(float), stream);

    crf_fwd<<<dim3(B_), dim3(256), 0, stream>>>(feats, trans, tags, mask, out);
}